// Round 1
// baseline (227.550 us; speedup 1.0000x reference)
//
#include <hip/hip_runtime.h>
#include <hip/hip_bf16.h>
#include <stdint.h>

#define B_ 32
#define S_ 8192
#define HD_ 256
#define HE_ 256
#define CHUNK 128
#define NCHUNK (S_/CHUNK)   /* 64 blocks per batch */
#define PSTRIDE 264         /* floats per partial record: 256 num + m + d + pad */

typedef __attribute__((ext_vector_type(8))) short bf16x8;
typedef __attribute__((ext_vector_type(4))) float f32x4;

__device__ __forceinline__ unsigned short f2bf(float f) {
  uint32_t u = __float_as_uint(f);
  u += 0x7FFFu + ((u >> 16) & 1u);          // round-to-nearest-even
  return (unsigned short)(u >> 16);
}
__device__ __forceinline__ float bf2f(unsigned short h) {
  return __uint_as_float(((uint32_t)h) << 16);
}
__device__ __forceinline__ float tanh_fast(float x) {
  // tanh(x) = 1 - 2/(exp(2x)+1); well-behaved at +/-inf, no NaN
  float e = __expf(2.0f * x);
  return 1.0f - 2.0f * __builtin_amdgcn_rcpf(e + 1.0f);
}

// ---------------- prep: qv[b,h] = q@Wa^T + Wa_b + Ua_b ; Ua -> bf16 ----------------
__global__ void prep_kernel(const float* __restrict__ query,
                            const float* __restrict__ Wa_w,
                            const float* __restrict__ Wa_b,
                            const float* __restrict__ Ua_w,
                            const float* __restrict__ Ua_b,
                            float* __restrict__ qv,
                            unsigned short* __restrict__ ua_bf) {
  const int blk = blockIdx.x, t = threadIdx.x;
  if (blk < B_) {
    __shared__ float qs[HD_];
    qs[t] = query[blk * HD_ + t];
    __syncthreads();
    const float* wr = Wa_w + (size_t)t * HD_;
    float s = Wa_b[t] + Ua_b[t];
#pragma unroll 8
    for (int d = 0; d < HD_; ++d) s += qs[d] * wr[d];
    qv[blk * HD_ + t] = s;
  } else {
    const int base = (blk - B_) * 2048 + t * 8;
    float4 v0 = *(const float4*)(Ua_w + base);
    float4 v1 = *(const float4*)(Ua_w + base + 4);
    uint4 pk;
    pk.x = (uint32_t)f2bf(v0.x) | ((uint32_t)f2bf(v0.y) << 16);
    pk.y = (uint32_t)f2bf(v0.z) | ((uint32_t)f2bf(v0.w) << 16);
    pk.z = (uint32_t)f2bf(v1.x) | ((uint32_t)f2bf(v1.y) << 16);
    pk.w = (uint32_t)f2bf(v1.z) | ((uint32_t)f2bf(v1.w) << 16);
    *(uint4*)(ua_bf + base) = pk;
  }
}

// ---------------- main: fused k_proj GEMM + tanh + score + online softmax partial ----------------
__global__ __launch_bounds__(256, 2)
void main_kernel(const float* __restrict__ keys,
                 const float* __restrict__ qv,
                 const float* __restrict__ Va_w,
                 const unsigned short* __restrict__ ua_bf,
                 float* __restrict__ scores,
                 float* __restrict__ partials) {
  // swizzled bf16 keys tile: byte off = row*512 + (inrow_byte ^ ((row&7)<<4))
  __shared__ __align__(16) char kt[CHUNK * HE_ * 2];   // 64 KB
  __shared__ float ssc[CHUNK];
  __shared__ float swe[CHUNK];
  __shared__ float sred[1];

  const int t = threadIdx.x;
  const int b = blockIdx.y;
  const int chunk = blockIdx.x;
  const int s0 = chunk * CHUNK;
  const float* kbase = keys + ((size_t)b * S_ + s0) * HE_;

  // ---- stage: 128x256 fp32 -> bf16 LDS (coalesced float4 loads) ----
#pragma unroll 4
  for (int it = 0; it < 32; ++it) {
    int f = it * 256 + t;                 // float4 index 0..8191 (64 per row)
    float4 v = ((const float4*)kbase)[f];
    int row = f >> 6;
    int off = row * 512 + (((f & 63) * 8) ^ ((row & 7) << 4));
    uint2 pk;
    pk.x = (uint32_t)f2bf(v.x) | ((uint32_t)f2bf(v.y) << 16);
    pk.y = (uint32_t)f2bf(v.z) | ((uint32_t)f2bf(v.w) << 16);
    *(uint2*)(kt + off) = pk;
  }
  __syncthreads();

  // ---- MFMA: each wave owns 32 rows (2 M-tiles of 16) ----
  const int lane = t & 63;
  const int w = t >> 6;
  const int ln = lane & 15;
  const int hi = lane >> 4;

  bf16x8 afr[2][8];
#pragma unroll
  for (int mt = 0; mt < 2; ++mt) {
    const int row = w * 32 + mt * 16 + ln;
    const int rb = row * 512;
    const int sw = (ln & 7) << 4;          // row%8 == ln%8 here
#pragma unroll
    for (int k = 0; k < 8; ++k) {
      int off = rb + ((k * 64 + hi * 16) ^ sw);
      afr[mt][k] = *(const bf16x8*)(kt + off);
    }
  }

  float part[2][4] = {{0.f,0.f,0.f,0.f},{0.f,0.f,0.f,0.f}};
  const unsigned short* ub = ua_bf + (size_t)ln * HE_ + hi * 8;
#pragma unroll 1
  for (int nt = 0; nt < 16; ++nt) {
    f32x4 acc0 = {0.f,0.f,0.f,0.f};
    f32x4 acc1 = {0.f,0.f,0.f,0.f};
    const unsigned short* ubn = ub + nt * 16 * HE_;
#pragma unroll
    for (int k = 0; k < 8; ++k) {
      bf16x8 bfr = *(const bf16x8*)(ubn + k * 32);
      acc0 = __builtin_amdgcn_mfma_f32_16x16x32_bf16(afr[0][k], bfr, acc0, 0, 0, 0);
      acc1 = __builtin_amdgcn_mfma_f32_16x16x32_bf16(afr[1][k], bfr, acc1, 0, 0, 0);
    }
    const int h = nt * 16 + ln;
    const float va = Va_w[h];
    const float q = qv[b * HD_ + h];
#pragma unroll
    for (int r = 0; r < 4; ++r) {
      part[0][r] += tanh_fast(acc0[r] + q) * va;
      part[1][r] += tanh_fast(acc1[r] + q) * va;
    }
  }

  // reduce the 16 h-columns per lane-group; lane ln==0 holds row score
#pragma unroll
  for (int mt = 0; mt < 2; ++mt) {
#pragma unroll
    for (int r = 0; r < 4; ++r) {
      float v = part[mt][r];
      v += __shfl_xor(v, 1, 64);
      v += __shfl_xor(v, 2, 64);
      v += __shfl_xor(v, 4, 64);
      v += __shfl_xor(v, 8, 64);
      if (ln == 0) {
        int row = w * 32 + mt * 16 + hi * 4 + r;
        ssc[row] = v;
        scores[(size_t)b * S_ + s0 + row] = v;
      }
    }
  }
  __syncthreads();

  // ---- block-local softmax partial + context numerator ----
  float m = -1e30f;
#pragma unroll 8
  for (int i = 0; i < CHUNK; ++i) m = fmaxf(m, ssc[i]);
  if (t < CHUNK) swe[t] = __expf(ssc[t] - m);
  __syncthreads();

  if (t < 64) {
    float v = swe[t] + swe[t + 64];
#pragma unroll
    for (int mm = 32; mm; mm >>= 1) v += __shfl_xor(v, mm, 64);
    if (t == 0) sred[0] = v;
  }

  // numerator: thread t owns column e=t (conflict-free: pairs share a word)
  float num = 0.f;
  {
    const int e2 = t * 2;
#pragma unroll 4
    for (int row = 0; row < CHUNK; ++row) {
      unsigned short kv = *(const unsigned short*)(kt + row * 512 + (e2 ^ ((row & 7) << 4)));
      num += swe[row] * bf2f(kv);
    }
  }
  __syncthreads();

  float* pp = partials + (size_t)(b * NCHUNK + chunk) * PSTRIDE;
  pp[t] = num;
  if (t == 0) { pp[256] = m; pp[257] = sred[0]; }
}

// ---------------- combine: merge partials, write context + weights ----------------
__global__ void combine_kernel(const float* __restrict__ partials,
                               const float* __restrict__ scores,
                               float* __restrict__ out) {
  __shared__ float sm[NCHUNK], ssd[NCHUNK], sscale[NCHUNK];
  const int b = blockIdx.x, t = threadIdx.x;
  const float* pb = partials + (size_t)b * NCHUNK * PSTRIDE;
  if (t < NCHUNK) {
    sm[t]  = pb[(size_t)t * PSTRIDE + 256];
    ssd[t] = pb[(size_t)t * PSTRIDE + 257];
  }
  __syncthreads();
  float mb = -1e30f;
#pragma unroll
  for (int i = 0; i < NCHUNK; ++i) mb = fmaxf(mb, sm[i]);
  if (t < NCHUNK) sscale[t] = __expf(sm[t] - mb);
  __syncthreads();
  float denom = 0.f;
#pragma unroll
  for (int i = 0; i < NCHUNK; ++i) denom += ssd[i] * sscale[i];
  const float rd = 1.0f / denom;

  // context: thread t owns e=t
  float num = 0.f;
#pragma unroll 4
  for (int i = 0; i < NCHUNK; ++i) num += pb[(size_t)i * PSTRIDE + t] * sscale[i];
  out[b * HE_ + t] = num * rd;

  // weights
  const float* sc = scores + (size_t)b * S_;
  float* wout = out + B_ * HE_ + (size_t)b * S_;
  for (int s = t; s < S_; s += 256) wout[s] = __expf(sc[s] - mb) * rd;
}

extern "C" void kernel_launch(void* const* d_in, const int* in_sizes, int n_in,
                              void* d_out, int out_size, void* d_ws, size_t ws_size,
                              hipStream_t stream) {
  const float* query = (const float*)d_in[0];
  const float* keys  = (const float*)d_in[1];
  const float* Wa_w  = (const float*)d_in[2];
  const float* Wa_b  = (const float*)d_in[3];
  const float* Ua_w  = (const float*)d_in[4];
  const float* Ua_b  = (const float*)d_in[5];
  const float* Va_w  = (const float*)d_in[6];
  // Va_b (d_in[7]) is a constant score shift: softmax-invariant, dropped.
  float* out = (float*)d_out;

  char* ws = (char*)d_ws;
  float* qv            = (float*)ws;                                  // 32 KB
  unsigned short* ua_bf = (unsigned short*)(ws + 32 * 1024);          // 128 KB
  float* scores        = (float*)(ws + 160 * 1024);                   // 1 MB
  float* partials      = (float*)(ws + 160 * 1024 + 1024 * 1024);     // ~2.1 MB

  prep_kernel<<<64, 256, 0, stream>>>(query, Wa_w, Wa_b, Ua_w, Ua_b, qv, ua_bf);
  dim3 g(NCHUNK, B_);
  main_kernel<<<g, 256, 0, stream>>>(keys, qv, Va_w, ua_bf, scores, partials);
  combine_kernel<<<B_, 256, 0, stream>>>(partials, scores, out);
}